// Round 9
// baseline (3059.068 us; speedup 1.0000x reference)
//
#include <hip/hip_runtime.h>

// ---------------------------------------------------------------------------
// 2-layer LSTM LM, S=512 B=512 H=256 V=128 — Round 9: split-exchange skew.
// 256 blocks = 32 batch-groups x 8 col-blocks, weights VGPR/AGPR-resident.
// Only the h0 exchange is latency-critical (publish h0_t -> consume t+1).
// Iter t: P1 poll/gather h0_{t-1}; P2 MFMA L0(t)+L1a(t-1); P3 epi0 ->
// publish h0_t -> drain -> tagH0 EARLY (peers unblock), with h1_{t-2}
// gather overlapped into the same drain (tagH1 has 1 iter slack -> never
// spins); P5 MFMA L1b(t-1)+proj(t-2); P6 epi1 -> publish h1_{t-1} -> tagH1;
// P7 out store. All P5-P7 work hides the h0 round-trip to peers.
// Slot safety: h0 2 slots (t&1); h1 2 slots (write (t+1)&1, read t&1) —
// valid because peers' h1 reads retire before their tagH0 store (drain).
// h fp16 hi/lo (~fp32); weights fp16; c fp32 in regs. Same map as R8.
// ---------------------------------------------------------------------------

#define S_ 512
#define B_ 512
#define H_ 256
#define V_ 128

typedef _Float16 f16;
typedef __attribute__((ext_vector_type(8))) _Float16 f16x8;
typedef __attribute__((ext_vector_type(4))) float f32x4;
typedef unsigned long long u64;
typedef unsigned u32;

// ws BYTE offsets
#define OFF_B0   0          // f16 frags [j8][w8][kk8][64][8]  = 512 KB (w_hh0)
#define OFF_B1   524288     // f16 frags [j8][w8][kk16][64][8] = 1 MB  (w_ih1|w_hh1)
#define OFF_BP   1572864    // f16 frags [j8][w8][64][8]       = 64 KB (W_out)
#define OFF_EX   1638400    // [bg32][slot2][layer2][16][256] f32 = 2 MB
#define OFF_TAG  3735552    // tagH0 [bg32][j8] (128B apart) = 32 KB; tagH1 follows (+32 KB)

__device__ __forceinline__ float sigm(float z) { return 1.0f / (1.0f + __expf(-z)); }
__device__ __forceinline__ float tanh_fast(float z) {
  return 2.0f / (1.0f + __expf(-2.0f * z)) - 1.0f;
}

// ---------------------------------------------------------------------------
// prep: pack weights into per-(colblock,wave) fp16 MFMA B-fragment streams;
// zero both tag arrays. B frag (16x16x32): lane l elem i -> B[k][n],
// k = kk*32+(l>>4)*8+i, n = l&15. Wave w of col-block j: gate=w>>1, half=w&1,
// hcol = j*32 + half*16 + n.
// ---------------------------------------------------------------------------
__global__ void prep_kernel(const float* __restrict__ w_hh0,
                            const float* __restrict__ w_ih1, const float* __restrict__ w_hh1,
                            const float* __restrict__ W_out, void* __restrict__ ws) {
  int idx = blockIdx.x * blockDim.x + threadIdx.x;
  f16* wsh = (f16*)ws;
  if (idx < 32768) {                                  // B0 (w_hh0)
    int j = idx >> 12, w = (idx >> 9) & 7, kk = (idx >> 6) & 7, lane = idx & 63;
    int gate = w >> 1, half = w & 1;
    int hcol = j * 32 + half * 16 + (lane & 15);
    int G = gate * H_ + hcol;
    int k0 = kk * 32 + (lane >> 4) * 8;
    f16x8 v;
    #pragma unroll
    for (int i = 0; i < 8; ++i) v[i] = (f16)w_hh0[G * H_ + k0 + i];
    *(f16x8*)(wsh + idx * 8) = v;
  } else if (idx < 32768 + 65536) {                   // B1 (K=512: w_ih1 | w_hh1)
    int t = idx - 32768;
    int j = t >> 13, w = (t >> 10) & 7, kk = (t >> 6) & 15, lane = t & 63;
    int gate = w >> 1, half = w & 1;
    int hcol = j * 32 + half * 16 + (lane & 15);
    int G = gate * H_ + hcol;
    int k0 = kk * 32 + (lane >> 4) * 8;
    const float* src = (k0 < H_) ? (w_ih1 + G * H_ + k0) : (w_hh1 + G * H_ + (k0 - H_));
    f16x8 v;
    #pragma unroll
    for (int i = 0; i < 8; ++i) v[i] = (f16)src[i];
    *(f16x8*)(wsh + 262144 + t * 8) = v;
  } else if (idx < 32768 + 65536 + 4096) {            // BP (W_out), kk = w
    int t = idx - (32768 + 65536);
    int j = t >> 9, w = (t >> 6) & 7, lane = t & 63;
    int vcol = j * 16 + (lane & 15);
    int k0 = w * 32 + (lane >> 4) * 8;
    f16x8 v;
    #pragma unroll
    for (int i = 0; i < 8; ++i) v[i] = (f16)W_out[vcol * H_ + k0 + i];
    *(f16x8*)(wsh + 786432 + t * 8) = v;
  } else if (idx < 32768 + 65536 + 4096 + 16384) {    // zero tagH0+tagH1 (64 KB)
    ((u32*)((char*)ws + OFF_TAG))[idx - 102400] = 0u;
  }
}

__device__ __forceinline__ u64 aload64(const u64* p) {
  return __hip_atomic_load((u64*)p, __ATOMIC_RELAXED, __HIP_MEMORY_SCOPE_AGENT);
}
__device__ __forceinline__ u32 aload32(const u32* p) {
  return __hip_atomic_load((u32*)p, __ATOMIC_RELAXED, __HIP_MEMORY_SCOPE_AGENT);
}
__device__ __forceinline__ void astore32(u32* p, u32 v) {
  __hip_atomic_store(p, v, __ATOMIC_RELAXED, __HIP_MEMORY_SCOPE_AGENT);
}
// 8 consecutive fp32 via relaxed agent loads (MALL-coherent path)
__device__ __forceinline__ void agather8(const float* p, f32x4& a, f32x4& b) {
  u64 q0 = aload64((const u64*)p),     q1 = aload64((const u64*)p + 1);
  u64 q2 = aload64((const u64*)p + 2), q3 = aload64((const u64*)p + 3);
  union { u32 u; float f; } c;
  c.u = (u32)q0; a[0] = c.f; c.u = (u32)(q0 >> 32); a[1] = c.f;
  c.u = (u32)q1; a[2] = c.f; c.u = (u32)(q1 >> 32); a[3] = c.f;
  c.u = (u32)q2; b[0] = c.f; c.u = (u32)(q2 >> 32); b[1] = c.f;
  c.u = (u32)q3; b[2] = c.f; c.u = (u32)(q3 >> 32); b[3] = c.f;
}

// convert 8 fp32 -> hi/lo f16 and store into frag-layout LDS at tid*16B
__device__ __forceinline__ void cvt8(f32x4 a, f32x4 b, f16* bh, f16* bl, int tid) {
  float f[8] = {a[0], a[1], a[2], a[3], b[0], b[1], b[2], b[3]};
  union { f16 h[8]; u64 v[2]; } Hh, Ll;
  #pragma unroll
  for (int i = 0; i < 8; ++i) {
    f16 hi = (f16)f[i];
    Hh.h[i] = hi;
    Ll.h[i] = (f16)(f[i] - (float)hi);
  }
  ((u64*)bh)[tid * 2]     = Hh.v[0];
  ((u64*)bh)[tid * 2 + 1] = Hh.v[1];
  ((u64*)bl)[tid * 2]     = Ll.v[0];
  ((u64*)bl)[tid * 2 + 1] = Ll.v[1];
}

// A-frag read, fragment-layout LDS: conflict-free (lane-consecutive 16B)
__device__ __forceinline__ f16x8 afrag(const f16* buf, int lane, int kk) {
  return *(const f16x8*)(buf + kk * 512 + lane * 8);
}

__global__ __launch_bounds__(512, 2) void lstm_r9(const int* __restrict__ x,
                                                  const f16* __restrict__ wts,
                                                  char* __restrict__ ex,
                                                  u32* __restrict__ tags,
                                                  const float* __restrict__ w_ih0,
                                                  const float* __restrict__ b_ih0,
                                                  const float* __restrict__ b_hh0,
                                                  const float* __restrict__ b_ih1,
                                                  const float* __restrict__ b_hh1,
                                                  const float* __restrict__ b_out,
                                                  float* __restrict__ out) {
  __shared__ __align__(16) f16 H0h[4096], H0l[4096], H1h[4096], H1l[4096]; // 32 KB
  __shared__ __align__(16) float gsc0[4][16][33];
  __shared__ __align__(16) float gsc1[4][16][33];
  __shared__ __align__(16) float ppart[4][8][64];

  const int tid  = threadIdx.x;
  const int lane = tid & 63;
  const int w    = tid >> 6;            // wave 0..7: gate = w>>1, half = w&1
  const int bg   = blockIdx.x >> 3;     // batch group 0..31 (16 rows)
  const int j    = blockIdx.x & 7;      // col block 0..7 (32 h-cols)

  // ---- persistent weight fragments (VGPR/AGPR resident) ----
  f16x8 B0r[8], B1r[16], BPr;
  {
    const f16* p0 = wts + (size_t)(j * 8 + w) * 8 * 512 + lane * 8;
    #pragma unroll
    for (int kk = 0; kk < 8; ++kk) B0r[kk] = *(const f16x8*)(p0 + kk * 512);
    const f16* p1 = wts + 262144 + (size_t)(j * 8 + w) * 16 * 512 + lane * 8;
    #pragma unroll
    for (int kk = 0; kk < 16; ++kk) B1r[kk] = *(const f16x8*)(p1 + kk * 512);
    BPr = *(const f16x8*)(wts + 786432 + (size_t)(j * 8 + w) * 512 + lane * 8);
  }

  // ---- per-thread epilogue constants: (erow = tid>>5, ecol = tid&31) ----
  const int erow = tid >> 5, ecol = tid & 31;
  const int hcol = j * 32 + ecol;
  const int browg = bg * 16 + erow;
  float wxv[4], bz0v[4], bz1v[4];
  #pragma unroll
  for (int g = 0; g < 4; ++g) {
    int G = g * H_ + hcol;
    wxv[g]  = w_ih0[G];
    bz0v[g] = b_ih0[G] + b_hh0[G];
    bz1v[g] = b_ih1[G] + b_hh1[G];
  }
  const float bo = (tid < 256) ? b_out[j * 16 + (tid & 15)] : 0.f;

  char* exG = ex + (size_t)bg * 65536;
  u32* tagB0 = tags + (size_t)bg * 8 * 32;            // tagH0, 128 B apart
  u32* myTag0   = tagB0 + j * 32;
  u32* peerTag0 = tagB0 + w * 32;                     // wave w owns peer w
  u32* myTag1   = myTag0 + 8192;                      // tagH1 array (+32 KB)
  u32* peerTag1 = peerTag0 + 8192;

  // gather indexing: wave w == peer w == frag tile kk=w
  const int grow = lane & 15;
  const int gcol = w * 32 + ((lane >> 4) << 3);

  float c0 = 0.f, c1 = 0.f;

  // zero LDS h buffers (h0_{-1} = h1_{-2} = 0)
  #pragma unroll
  for (int i = 0; i < 2; ++i) {
    ((u64*)H0h)[tid + i * 512] = 0ull; ((u64*)H0l)[tid + i * 512] = 0ull;
    ((u64*)H1h)[tid + i * 512] = 0ull; ((u64*)H1l)[tid + i * 512] = 0ull;
  }
  __syncthreads();

  #pragma unroll 1
  for (int t = 0; t <= S_ + 1; ++t) {
    // x for this thread's row (issued before poll -> overlaps sync latency)
    float xf = (t < S_) ? (float)x[t * B_ + browg] : 0.f;

    // ---- P1: poll h0 tag (the ONLY tight sync), gather + stage h0_{t-1} --
    if (t > 0) {
      const u32 need = (u32)t;
      while (aload32(peerTag0) < need) __builtin_amdgcn_s_sleep(1);
      asm volatile("" ::: "memory");
      const float* s0 = (const float*)(exG + ((t - 1) & 1) * 32768);
      f32x4 a0, a1;
      agather8(s0 + grow * 256 + gcol, a0, a1);
      cvt8(a0, a1, H0h, H0l, tid);
    }
    __syncthreads();                                  // B1

    // ---- P2: MFMA L0(t) + L1 first half (both read h0_{t-1}) ----
    f32x4 acc0 = {0.f, 0.f, 0.f, 0.f};
    f32x4 acc1 = {0.f, 0.f, 0.f, 0.f};
    #pragma unroll
    for (int kk = 0; kk < 8; ++kk) {
      f16x8 ah = afrag(H0h, lane, kk), al = afrag(H0l, lane, kk);
      acc0 = __builtin_amdgcn_mfma_f32_16x16x32_f16(ah, B0r[kk], acc0, 0, 0, 0);
      acc0 = __builtin_amdgcn_mfma_f32_16x16x32_f16(al, B0r[kk], acc0, 0, 0, 0);
      acc1 = __builtin_amdgcn_mfma_f32_16x16x32_f16(ah, B1r[kk], acc1, 0, 0, 0);
      acc1 = __builtin_amdgcn_mfma_f32_16x16x32_f16(al, B1r[kk], acc1, 0, 0, 0);
    }
    {
      const int gate = w >> 1, half = w & 1;
      const int c16 = lane & 15, r0 = (lane >> 4) * 4;
      #pragma unroll
      for (int r = 0; r < 4; ++r) gsc0[gate][r0 + r][half * 16 + c16] = acc0[r];
    }
    __syncthreads();                                  // B2

    // ---- P3: overlap h1 gather with epi0 + h0 publish; drain; tagH0 ----
    f32x4 d0 = {0.f, 0.f, 0.f, 0.f}, d1 = {0.f, 0.f, 0.f, 0.f};
    if (t > 0) {
      const u32 need = (u32)t;                        // 1-iter slack: rarely spins
      while (aload32(peerTag1) < need) __builtin_amdgcn_s_sleep(1);
      asm volatile("" ::: "memory");
      const float* s1 = (const float*)(exG + (t & 1) * 32768) + 4096;
      agather8(s1 + grow * 256 + gcol, d0, d1);       // h1_{t-2}, in flight
    }
    if (t < S_) {                                     // epi0 -> h0_t, publish
      float gi = gsc0[0][erow][ecol] + xf * wxv[0] + bz0v[0];
      float gf = gsc0[1][erow][ecol] + xf * wxv[1] + bz0v[1];
      float gg = gsc0[2][erow][ecol] + xf * wxv[2] + bz0v[2];
      float go = gsc0[3][erow][ecol] + xf * wxv[3] + bz0v[3];
      c0 = sigm(gf) * c0 + sigm(gi) * tanh_fast(gg);
      float h0 = sigm(go) * tanh_fast(c0);
      union { float f; u32 u; } hb; hb.f = h0;
      astore32((u32*)(exG + (t & 1) * 32768) + erow * 256 + hcol, hb.u);
    }
    asm volatile("s_waitcnt vmcnt(0)" ::: "memory");  // h0 stores + h1 loads retired
    if (t > 0) cvt8(d0, d1, H1h, H1l, tid);           // stage h1_{t-2}
    __syncthreads();                                  // B3
    if (tid == 0 && t <= S_) astore32(myTag0, (u32)(t + 1));   // peers unblock NOW

    // ---- P5: MFMA L1 second half (h1_{t-2}) + proj(t-2) — off critical path
    #pragma unroll
    for (int kk = 0; kk < 8; ++kk) {
      f16x8 ah = afrag(H1h, lane, kk), al = afrag(H1l, lane, kk);
      acc1 = __builtin_amdgcn_mfma_f32_16x16x32_f16(ah, B1r[kk + 8], acc1, 0, 0, 0);
      acc1 = __builtin_amdgcn_mfma_f32_16x16x32_f16(al, B1r[kk + 8], acc1, 0, 0, 0);
    }
    {
      f32x4 ap = {0.f, 0.f, 0.f, 0.f};
      f16x8 ah = afrag(H1h, lane, w), al = afrag(H1l, lane, w);
      ap = __builtin_amdgcn_mfma_f32_16x16x32_f16(ah, BPr, ap, 0, 0, 0);
      ap = __builtin_amdgcn_mfma_f32_16x16x32_f16(al, BPr, ap, 0, 0, 0);
      const int gate = w >> 1, half = w & 1;
      const int c16 = lane & 15, r0 = (lane >> 4) * 4;
      #pragma unroll
      for (int r = 0; r < 4; ++r) {
        gsc1[gate][r0 + r][half * 16 + c16] = acc1[r];
        ppart[r][w][lane] = ap[r];
      }
    }
    __syncthreads();                                  // B5

    // ---- P6: epi1 -> h1_{t-1}, publish into slot (t+1)&1; drain; tagH1 ----
    if (t <= S_) {
      float h1 = 0.f;
      if (t >= 1) {
        float gi = gsc1[0][erow][ecol] + bz1v[0];
        float gf = gsc1[1][erow][ecol] + bz1v[1];
        float gg = gsc1[2][erow][ecol] + bz1v[2];
        float go = gsc1[3][erow][ecol] + bz1v[3];
        c1 = sigm(gf) * c1 + sigm(gi) * tanh_fast(gg);
        h1 = sigm(go) * tanh_fast(c1);
      }
      union { float f; u32 u; } hb; hb.f = h1;
      astore32((u32*)(exG + ((t + 1) & 1) * 32768) + 4096 + erow * 256 + hcol, hb.u);
      asm volatile("s_waitcnt vmcnt(0)" ::: "memory");
    }
    __syncthreads();                                  // B6
    if (tid == 0 && t <= S_) astore32(myTag1, (u32)(t + 1));

    // ---- P7: out store for step t-2 (fully off critical path) ----
    if (t >= 2 && tid < 256) {
      int prow = tid >> 4, pvc = tid & 15;
      int plane = (prow >> 2) * 16 + pvc, preg = prow & 3;
      float s = bo;
      #pragma unroll
      for (int ww = 0; ww < 8; ++ww) s += ppart[preg][ww][plane];
      out[((size_t)((t - 2) * B_ + bg * 16 + prow)) * V_ + j * 16 + pvc] = s;
    }
  }
}

extern "C" void kernel_launch(void* const* d_in, const int* in_sizes, int n_in,
                              void* d_out, int out_size, void* d_ws, size_t ws_size,
                              hipStream_t stream) {
  const int*   x     = (const int*)d_in[0];
  const float* w_ih0 = (const float*)d_in[1];
  const float* w_hh0 = (const float*)d_in[2];
  const float* b_ih0 = (const float*)d_in[3];
  const float* b_hh0 = (const float*)d_in[4];
  const float* w_ih1 = (const float*)d_in[5];
  const float* w_hh1 = (const float*)d_in[6];
  const float* b_ih1 = (const float*)d_in[7];
  const float* b_hh1 = (const float*)d_in[8];
  const float* W_out = (const float*)d_in[9];
  const float* b_out = (const float*)d_in[10];

  // prep threads: 32768 + 65536 + 4096 + 16384 = 118784 = 464 * 256
  prep_kernel<<<464, 256, 0, stream>>>(w_hh0, w_ih1, w_hh1, W_out, d_ws);

  lstm_r9<<<256, 512, 0, stream>>>(x, (const f16*)d_ws,
                                   (char*)d_ws + OFF_EX, (u32*)((char*)d_ws + OFF_TAG),
                                   w_ih0, b_ih0, b_hh0, b_ih1, b_hh1, b_out,
                                   (float*)d_out);
}

// Round 10
// 1911.376 us; speedup vs baseline: 1.6005x; 1.6005x over previous
//
#include <hip/hip_runtime.h>

// ---------------------------------------------------------------------------
// 2-layer LSTM LM, S=512 B=512 H=256 V=128 — Round 10: R8 schedule (proven
// fastest) + single-fp16 h. 256 blocks = 32 batch-groups x 8 col-blocks,
// weights VGPR/AGPR-resident fp16 MFMA B-fragments. Skewed schedule per iter
// t: gather h0_{t-1},h1_{t-2} -> MFMA L0(t)+L1(t-1)+proj(t-2) -> epilogues ->
// publish h0_t,h1_{t-1} (fp16, relaxed agent stores) -> vmcnt(0) drain ->
// barrier -> tag. Per-wave poll (wave w owns peer w == frag tile kk=w).
// h is SINGLE fp16 now: gathered bits are directly the MFMA A-fragment
// payload (no cvt), 25 MFMAs/iter (was 66), exchange volume halved.
// c stays fp32 in registers; weights fp16 (the 2^-9 error floor).
// ---------------------------------------------------------------------------

#define S_ 512
#define B_ 512
#define H_ 256
#define V_ 128

typedef _Float16 f16;
typedef __attribute__((ext_vector_type(8))) _Float16 f16x8;
typedef __attribute__((ext_vector_type(4))) float f32x4;
typedef unsigned long long u64;
typedef unsigned u32;
typedef unsigned short u16;

// ws BYTE offsets
#define OFF_B0   0          // f16 frags [j8][w8][kk8][64][8]  = 512 KB (w_hh0)
#define OFF_B1   524288     // f16 frags [j8][w8][kk16][64][8] = 1 MB  (w_ih1|w_hh1)
#define OFF_BP   1572864    // f16 frags [j8][w8][64][8]       = 64 KB (W_out)
#define OFF_EX   1638400    // [bg32][slot2][layer2][16][256] f16 = 1 MB
#define OFF_TAG  2686976    // [bg32][j8] u32, one per 128 B = 32 KB

__device__ __forceinline__ float sigm(float z) { return 1.0f / (1.0f + __expf(-z)); }
__device__ __forceinline__ float tanh_fast(float z) {
  return 2.0f / (1.0f + __expf(-2.0f * z)) - 1.0f;
}

// ---------------------------------------------------------------------------
// prep: pack weights into per-(colblock,wave) fp16 MFMA B-fragment streams;
// zero tags. B frag (16x16x32): lane l elem i -> B[k][n],
// k = kk*32+(l>>4)*8+i, n = l&15. Wave w of col-block j: gate=w>>1, half=w&1,
// hcol = j*32 + half*16 + n.
// ---------------------------------------------------------------------------
__global__ void prep_kernel(const float* __restrict__ w_hh0,
                            const float* __restrict__ w_ih1, const float* __restrict__ w_hh1,
                            const float* __restrict__ W_out, void* __restrict__ ws) {
  int idx = blockIdx.x * blockDim.x + threadIdx.x;
  f16* wsh = (f16*)ws;
  if (idx < 32768) {                                  // B0 (w_hh0)
    int j = idx >> 12, w = (idx >> 9) & 7, kk = (idx >> 6) & 7, lane = idx & 63;
    int gate = w >> 1, half = w & 1;
    int hcol = j * 32 + half * 16 + (lane & 15);
    int G = gate * H_ + hcol;
    int k0 = kk * 32 + (lane >> 4) * 8;
    f16x8 v;
    #pragma unroll
    for (int i = 0; i < 8; ++i) v[i] = (f16)w_hh0[G * H_ + k0 + i];
    *(f16x8*)(wsh + idx * 8) = v;
  } else if (idx < 32768 + 65536) {                   // B1 (K=512: w_ih1 | w_hh1)
    int t = idx - 32768;
    int j = t >> 13, w = (t >> 10) & 7, kk = (t >> 6) & 15, lane = t & 63;
    int gate = w >> 1, half = w & 1;
    int hcol = j * 32 + half * 16 + (lane & 15);
    int G = gate * H_ + hcol;
    int k0 = kk * 32 + (lane >> 4) * 8;
    const float* src = (k0 < H_) ? (w_ih1 + G * H_ + k0) : (w_hh1 + G * H_ + (k0 - H_));
    f16x8 v;
    #pragma unroll
    for (int i = 0; i < 8; ++i) v[i] = (f16)src[i];
    *(f16x8*)(wsh + 262144 + t * 8) = v;
  } else if (idx < 32768 + 65536 + 4096) {            // BP (W_out), kk = w
    int t = idx - (32768 + 65536);
    int j = t >> 9, w = (t >> 6) & 7, lane = t & 63;
    int vcol = j * 16 + (lane & 15);
    int k0 = w * 32 + (lane >> 4) * 8;
    f16x8 v;
    #pragma unroll
    for (int i = 0; i < 8; ++i) v[i] = (f16)W_out[vcol * H_ + k0 + i];
    *(f16x8*)(wsh + 786432 + t * 8) = v;
  } else if (idx < 32768 + 65536 + 4096 + 8192) {     // zero tags (32 KB)
    ((u32*)((char*)ws + OFF_TAG))[idx - 102400] = 0u;
  }
}

__device__ __forceinline__ u64 aload64(const u64* p) {
  return __hip_atomic_load((u64*)p, __ATOMIC_RELAXED, __HIP_MEMORY_SCOPE_AGENT);
}
__device__ __forceinline__ u32 aload32(const u32* p) {
  return __hip_atomic_load((u32*)p, __ATOMIC_RELAXED, __HIP_MEMORY_SCOPE_AGENT);
}
__device__ __forceinline__ void astore32(u32* p, u32 v) {
  __hip_atomic_store(p, v, __ATOMIC_RELAXED, __HIP_MEMORY_SCOPE_AGENT);
}
__device__ __forceinline__ void astore16(u16* p, u16 v) {
  __hip_atomic_store(p, v, __ATOMIC_RELAXED, __HIP_MEMORY_SCOPE_AGENT);
}

// A-frag read, fragment-layout LDS: conflict-free (lane-consecutive 16B)
__device__ __forceinline__ f16x8 afrag(const f16* buf, int lane, int kk) {
  return *(const f16x8*)(buf + kk * 512 + lane * 8);
}

__global__ __launch_bounds__(512, 2) void lstm_r10(const int* __restrict__ x,
                                                   const f16* __restrict__ wts,
                                                   char* __restrict__ ex,
                                                   u32* __restrict__ tags,
                                                   const float* __restrict__ w_ih0,
                                                   const float* __restrict__ b_ih0,
                                                   const float* __restrict__ b_hh0,
                                                   const float* __restrict__ b_ih1,
                                                   const float* __restrict__ b_hh1,
                                                   const float* __restrict__ b_out,
                                                   float* __restrict__ out) {
  __shared__ __align__(16) f16 H0[4096], H1[4096];    // 16 KB, frag layout
  __shared__ __align__(16) float gsc0[4][16][33];
  __shared__ __align__(16) float gsc1[4][16][33];
  __shared__ __align__(16) float ppart[4][8][64];

  const int tid  = threadIdx.x;
  const int lane = tid & 63;
  const int w    = tid >> 6;            // wave 0..7: gate = w>>1, half = w&1
  const int bg   = blockIdx.x >> 3;     // batch group 0..31 (16 rows)
  const int j    = blockIdx.x & 7;      // col block 0..7 (32 h-cols)

  // ---- persistent weight fragments (VGPR/AGPR resident) ----
  f16x8 B0r[8], B1r[16], BPr;
  {
    const f16* p0 = wts + (size_t)(j * 8 + w) * 8 * 512 + lane * 8;
    #pragma unroll
    for (int kk = 0; kk < 8; ++kk) B0r[kk] = *(const f16x8*)(p0 + kk * 512);
    const f16* p1 = wts + 262144 + (size_t)(j * 8 + w) * 16 * 512 + lane * 8;
    #pragma unroll
    for (int kk = 0; kk < 16; ++kk) B1r[kk] = *(const f16x8*)(p1 + kk * 512);
    BPr = *(const f16x8*)(wts + 786432 + (size_t)(j * 8 + w) * 512 + lane * 8);
  }

  // ---- per-thread epilogue constants: (erow = tid>>5, ecol = tid&31) ----
  const int erow = tid >> 5, ecol = tid & 31;
  const int hcol = j * 32 + ecol;
  const int browg = bg * 16 + erow;
  float wxv[4], bz0v[4], bz1v[4];
  #pragma unroll
  for (int g = 0; g < 4; ++g) {
    int G = g * H_ + hcol;
    wxv[g]  = w_ih0[G];
    bz0v[g] = b_ih0[G] + b_hh0[G];
    bz1v[g] = b_ih1[G] + b_hh1[G];
  }
  const float bo = (tid < 256) ? b_out[j * 16 + (tid & 15)] : 0.f;

  char* exG = ex + (size_t)bg * 32768;                // per-group 32 KB
  u32* tagB = tags + (size_t)bg * 8 * 32;             // 128 B apart
  u32* myTag = tagB + j * 32;
  u32* peerTag = tagB + w * 32;                       // wave w owns peer w

  // gather indexing: wave w == peer w == frag tile kk=w; 16B fp16 per thread
  const int grow = lane & 15;
  const int gbyte = grow * 512 + w * 64 + ((lane >> 4) << 4);  // byte offset in [16][256] f16

  float c0 = 0.f, c1 = 0.f;

  // zero LDS h buffers (h0_{-1} = h1_{-2} = 0)
  ((u64*)H0)[tid] = 0ull; ((u64*)H0)[tid + 512] = 0ull;
  ((u64*)H1)[tid] = 0ull; ((u64*)H1)[tid + 512] = 0ull;
  __syncthreads();

  #pragma unroll 1
  for (int t = 0; t <= S_ + 1; ++t) {
    // x for this thread's row (issued before poll -> overlaps sync latency)
    float xf = (t < S_) ? (float)x[t * B_ + browg] : 0.f;

    // ---- (1) per-wave relaxed poll of peer w, then gather tile kk=w ----
    if (t > 0) {
      const u32 need = (u32)t;
      while (aload32(peerTag) < need) __builtin_amdgcn_s_sleep(1);
      asm volatile("" ::: "memory");    // compiler barrier: no hoist/sink
      const char* slotR = exG + ((t - 1) & 1) * 16384;
      // h0_{t-1} (layer 0) and h1_{t-2} (layer 1): bits are already fp16
      // A-fragment payload -> straight to LDS, no conversion.
      u64 q0 = aload64((const u64*)(slotR + gbyte));
      u64 q1 = aload64((const u64*)(slotR + gbyte) + 1);
      u64 q2 = aload64((const u64*)(slotR + 8192 + gbyte));
      u64 q3 = aload64((const u64*)(slotR + 8192 + gbyte) + 1);
      ((u64*)H0)[tid * 2]     = q0;
      ((u64*)H0)[tid * 2 + 1] = q1;
      ((u64*)H1)[tid * 2]     = q2;
      ((u64*)H1)[tid * 2 + 1] = q3;
    }
    __syncthreads();

    // ---- (2) MFMA: L0(t), L1(t-1), proj(t-2) — 25 MFMAs ----
    {
      f32x4 acc0 = {0.f, 0.f, 0.f, 0.f};
      f32x4 acc1 = {0.f, 0.f, 0.f, 0.f};
      f32x4 ap   = {0.f, 0.f, 0.f, 0.f};
      #pragma unroll
      for (int kk = 0; kk < 8; ++kk) {
        f16x8 ah = afrag(H0, lane, kk);
        acc0 = __builtin_amdgcn_mfma_f32_16x16x32_f16(ah, B0r[kk], acc0, 0, 0, 0);
        acc1 = __builtin_amdgcn_mfma_f32_16x16x32_f16(ah, B1r[kk], acc1, 0, 0, 0);
      }
      #pragma unroll
      for (int kk = 0; kk < 8; ++kk) {
        f16x8 ah = afrag(H1, lane, kk);
        acc1 = __builtin_amdgcn_mfma_f32_16x16x32_f16(ah, B1r[kk + 8], acc1, 0, 0, 0);
      }
      ap = __builtin_amdgcn_mfma_f32_16x16x32_f16(afrag(H1, lane, w), BPr, ap, 0, 0, 0);
      const int gate = w >> 1, half = w & 1;
      const int c16 = lane & 15, r0 = (lane >> 4) * 4;
      #pragma unroll
      for (int r = 0; r < 4; ++r) {
        gsc0[gate][r0 + r][half * 16 + c16] = acc0[r];
        gsc1[gate][r0 + r][half * 16 + c16] = acc1[r];
        ppart[r][w][lane] = ap[r];
      }
    }
    __syncthreads();

    // ---- (3) epilogues + publishes into slot[t&1] (fp16 agent stores) ----
    u16* slotW = (u16*)(exG + (t & 1) * 16384);
    if (t < S_) {                         // layer0 step t -> h0_t
      float gi = gsc0[0][erow][ecol] + xf * wxv[0] + bz0v[0];
      float gf = gsc0[1][erow][ecol] + xf * wxv[1] + bz0v[1];
      float gg = gsc0[2][erow][ecol] + xf * wxv[2] + bz0v[2];
      float go = gsc0[3][erow][ecol] + xf * wxv[3] + bz0v[3];
      c0 = sigm(gf) * c0 + sigm(gi) * tanh_fast(gg);
      float h0 = sigm(go) * tanh_fast(c0);
      union { f16 h; u16 u; } hb; hb.h = (f16)h0;
      astore16(slotW + erow * 256 + hcol, hb.u);
    }
    if (t <= S_) {                        // layer1 step t-1 -> h1_{t-1}
      float h1 = 0.f;
      if (t >= 1) {
        float gi = gsc1[0][erow][ecol] + bz1v[0];
        float gf = gsc1[1][erow][ecol] + bz1v[1];
        float gg = gsc1[2][erow][ecol] + bz1v[2];
        float go = gsc1[3][erow][ecol] + bz1v[3];
        c1 = sigm(gf) * c1 + sigm(gi) * tanh_fast(gg);
        h1 = sigm(go) * tanh_fast(c1);
      }
      union { f16 h; u16 u; } hb; hb.h = (f16)h1;
      astore16(slotW + 4096 + erow * 256 + hcol, hb.u);
    }
    if (t >= 2 && tid < 256) {            // projection step t-2 -> out
      int prow = tid >> 4, pvc = tid & 15;
      int plane = (prow >> 2) * 16 + pvc, preg = prow & 3;
      float s = bo;
      #pragma unroll
      for (int ww = 0; ww < 8; ++ww) s += ppart[preg][ww][plane];
      out[((size_t)((t - 2) * B_ + bg * 16 + prow)) * V_ + j * 16 + pvc] = s;
    }

    // ---- (4) per-wave drain, barrier, then single relaxed tag store ----
    if (t <= S_) {
      asm volatile("s_waitcnt vmcnt(0)" ::: "memory");
      __syncthreads();                    // all waves' publishes are visible
      if (tid == 0) astore32(myTag, (u32)(t + 1));
    }
  }
}

extern "C" void kernel_launch(void* const* d_in, const int* in_sizes, int n_in,
                              void* d_out, int out_size, void* d_ws, size_t ws_size,
                              hipStream_t stream) {
  const int*   x     = (const int*)d_in[0];
  const float* w_ih0 = (const float*)d_in[1];
  const float* w_hh0 = (const float*)d_in[2];
  const float* b_ih0 = (const float*)d_in[3];
  const float* b_hh0 = (const float*)d_in[4];
  const float* w_ih1 = (const float*)d_in[5];
  const float* w_hh1 = (const float*)d_in[6];
  const float* b_ih1 = (const float*)d_in[7];
  const float* b_hh1 = (const float*)d_in[8];
  const float* W_out = (const float*)d_in[9];
  const float* b_out = (const float*)d_in[10];

  // prep threads: 32768 + 65536 + 4096 + 8192 = 110592 = 432 * 256
  prep_kernel<<<432, 256, 0, stream>>>(w_hh0, w_ih1, w_hh1, W_out, d_ws);

  lstm_r10<<<256, 512, 0, stream>>>(x, (const f16*)d_ws,
                                    (char*)d_ws + OFF_EX, (u32*)((char*)d_ws + OFF_TAG),
                                    w_ih0, b_ih0, b_hh0, b_ih1, b_hh1, b_out,
                                    (float*)d_out);
}